// Round 10
// baseline (1467.850 us; speedup 1.0000x reference)
//
#include <hip/hip_runtime.h>
#include <hip/hip_bf16.h>
#include <math.h>

typedef unsigned short u16t;
typedef unsigned int   u32t;
typedef __attribute__((ext_vector_type(8))) short  short8;   // 8 bf16 (4 VGPRs)
typedef __attribute__((ext_vector_type(4))) float  floatx4;  // MFMA acc

#define NPTS   8192
#define DMODEL 256
#define BNTOT  16384
#define FR     65536      // frag elements per matrix

__device__ __forceinline__ float bitsf(u32t u){ union { u32t i; float f; } v; v.i = u; return v.f; }
__device__ __forceinline__ float b2f(u16t s){ return bitsf(((u32t)s) << 16); }
__device__ __forceinline__ u16t f2b(float f){
  __hip_bfloat16 h = __float2bfloat16(f);
  return *reinterpret_cast<u16t*>(&h);
}
__device__ __forceinline__ uint4 pack8(const float* o){
  uint4 st;
  st.x = (u32t)f2b(o[0]) | ((u32t)f2b(o[1]) << 16);
  st.y = (u32t)f2b(o[2]) | ((u32t)f2b(o[3]) << 16);
  st.z = (u32t)f2b(o[4]) | ((u32t)f2b(o[5]) << 16);
  st.w = (u32t)f2b(o[6]) | ((u32t)f2b(o[7]) << 16);
  return st;
}
__device__ __forceinline__ float gelu_exact(float x){
  return 0.5f * x * (1.0f + erff(x * 0.70710678118654752f));
}

__global__ __launch_bounds__(256) void fill_valf(float* p, int n, float v){
  int i = blockIdx.x * 256 + threadIdx.x;
  if (i < n) p[i] = v;
}

// -------------------------------------------------- weight fragment prepack
// frag element ((ic*16+cca)*64 + lane)*8 + v = W[ic*32+(lane>>4)*8+v][cca*16+(lane&15)]
// mats: 0=Wk, 1=Wv, 2=Wp2, 3=Wo
__global__ __launch_bounds__(256) void wprep(const float* __restrict__ Wk,
                                             const float* __restrict__ Wv,
                                             const float* __restrict__ Wp2,
                                             const float* __restrict__ Wo,
                                             u16t* __restrict__ frags) {
  int e = blockIdx.x * 256 + threadIdx.x;        // 0..262143
  int m = e >> 16, r = e & 65535;
  const float* W = (m == 0) ? Wk : (m == 1) ? Wv : (m == 2) ? Wp2 : Wo;
  int v = r & 7, l = (r >> 3) & 63, cca = (r >> 9) & 15, ic = r >> 13;
  int i = ic * 32 + (l >> 4) * 8 + v;
  int c = cca * 16 + (l & 15);
  frags[(size_t)m * FR + r] = f2b(W[(size_t)i * DMODEL + c]);
}

// ---------------------------------------------------------------- kNN partial
// 8 chunks of 1024; register top-16 (sorted, stable); pd/pi transposed
// [slot][query] so stores (and merge loads) are coalesced.
__global__ __launch_bounds__(256) void knn_partial(const float* __restrict__ coords,
                                                   float* __restrict__ pd,
                                                   int* __restrict__ pi) {
  int qb = blockIdx.x >> 3, ch = blockIdx.x & 7;
  int tid = threadIdx.x;
  int g = qb * 256 + tid;
  int b = g >> 13;
  alignas(16) __shared__ float4 tile[256];

  float qx = coords[(size_t)g * 3 + 0];
  float qy = coords[(size_t)g * 3 + 1];
  float qz = coords[(size_t)g * 3 + 2];
  float qd2 = __fadd_rn(__fadd_rn(__fmul_rn(qx,qx), __fmul_rn(qy,qy)), __fmul_rn(qz,qz));

  float bd[16]; int bi[16];
  #pragma unroll
  for (int s = 0; s < 16; ++s) { bd[s] = 3e38f; bi[s] = 0x7fffffff; }

  int cs = ch * 1024;
  for (int t = 0; t < 4; ++t) {
    int ci = cs + t * 256 + tid;
    size_t cb = (size_t)(b * NPTS + ci) * 3;
    float x = coords[cb + 0];
    float y = coords[cb + 1];
    float z = coords[cb + 2];
    float d2 = __fadd_rn(__fadd_rn(__fmul_rn(x,x), __fmul_rn(y,y)), __fmul_rn(z,z));
    __syncthreads();
    tile[tid] = make_float4(x, y, z, d2);
    __syncthreads();
    int cbase = cs + t * 256;
    for (int u = 0; u < 256; ++u) {
      float4 cd = tile[u];
      float dot = __fadd_rn(__fadd_rn(__fmul_rn(qx,cd.x), __fmul_rn(qy,cd.y)), __fmul_rn(qz,cd.z));
      float dist = __fsub_rn(__fadd_rn(qd2, cd.w), __fmul_rn(2.0f, dot));
      if (dist < bd[15]) {
        bd[15] = dist; bi[15] = cbase + u;
        #pragma unroll
        for (int s = 15; s > 0; --s) {
          if (bd[s] < bd[s-1]) {
            float td = bd[s]; bd[s] = bd[s-1]; bd[s-1] = td;
            int   ti = bi[s]; bi[s] = bi[s-1]; bi[s-1] = ti;
          }
        }
      }
    }
  }
  #pragma unroll
  for (int s = 0; s < 16; ++s) {
    pd[(size_t)(ch * 16 + s) * BNTOT + g] = bd[s];
    pi[(size_t)(ch * 16 + s) * BNTOT + g] = bi[s];
  }
}

// ---------------------------------------------------------------- kNN merge
__global__ __launch_bounds__(256) void knn_merge(const float* __restrict__ pd,
                                                 const int* __restrict__ pi,
                                                 u16t* __restrict__ idxb) {
  int g = blockIdx.x * 256 + threadIdx.x;
  int h[8];
  #pragma unroll
  for (int c = 0; c < 8; ++c) h[c] = 0;
  for (int s = 0; s < 16; ++s) {
    float bdv = 3.3e38f; int bix = 0x7fffffff; int bc = 0;
    #pragma unroll
    for (int c = 0; c < 8; ++c) {
      if (h[c] < 16) {
        float dd = pd[(size_t)(c * 16 + h[c]) * BNTOT + g];
        int   ii = pi[(size_t)(c * 16 + h[c]) * BNTOT + g];
        if (dd < bdv || (dd == bdv && ii < bix)) { bdv = dd; bix = ii; bc = c; }
      }
    }
    idxb[(size_t)g * 16 + s] = (u16t)bix;
    h[bc]++;
  }
}

// ----------------------------------------------------------- K/V GEMM (MFMA)
__global__ __launch_bounds__(256) void gemm_kv_mfma(const float* __restrict__ feat,
    const u16t* __restrict__ frags,
    const float* __restrict__ bk, const float* __restrict__ bv,
    u16t* __restrict__ kb, u16t* __restrict__ vb) {
  int mat = blockIdx.y;
  const u16t* wf    = frags + (size_t)mat * FR;
  const float* bias = mat ? bv : bk;
  u16t* out         = mat ? vb : kb;

  int rbase = blockIdx.x * 64;
  int tid = threadIdx.x, lane = tid & 63, wvi = tid >> 6;
  int quad = lane >> 4, l15 = lane & 15;

  alignas(16) __shared__ u16t featS[64 * 264];

  {
    int r = tid >> 2, c0 = (tid & 3) * 64;
    const float* src = feat + (size_t)(rbase + r) * DMODEL + c0;
    u16t* dst = featS + r * 264 + c0;
    #pragma unroll
    for (int t = 0; t < 8; ++t) {
      float4 a = *(const float4*)(src + t * 8);
      float4 b = *(const float4*)(src + t * 8 + 4);
      float o[8] = {a.x, a.y, a.z, a.w, b.x, b.y, b.z, b.w};
      *(uint4*)(dst + t * 8) = pack8(o);
    }
  }
  __syncthreads();

  floatx4 acc[16];
  #pragma unroll
  for (int ct = 0; ct < 16; ++ct) acc[ct] = (floatx4){0.f, 0.f, 0.f, 0.f};

  #pragma unroll
  for (int ic = 0; ic < 8; ++ic) {
    short8 af = *(const short8*)(featS + (wvi * 16 + l15) * 264 + ic * 32 + quad * 8);
    #pragma unroll
    for (int ct = 0; ct < 16; ++ct) {
      short8 bf = *(const short8*)(wf + (((size_t)(ic * 16 + ct) * 64 + lane) << 3));
      acc[ct] = __builtin_amdgcn_mfma_f32_16x16x32_bf16(af, bf, acc[ct], 0, 0, 0);
    }
  }

  #pragma unroll
  for (int ct = 0; ct < 16; ++ct) {
    int col = ct * 16 + l15;
    float bvv = bias[col];
    #pragma unroll
    for (int r = 0; r < 4; ++r) {
      int row = rbase + wvi * 16 + quad * 4 + r;
      out[(size_t)row * DMODEL + col] = f2b(acc[ct][r] + bvv);
    }
  }
}

// -------------------------------------------------------------- mega kernel
// v4: query pairs, k/v prefetch at loop top, MFMA emb GEMM (A from LDS inside
// loop), MFMA out-projection. Thread = channel c; 4 waves = 8 queries.
#define HSTR 264
__global__ __launch_bounds__(256, 4) void attn_mega(
    const float* __restrict__ coords, const float* __restrict__ normals,
    const float* __restrict__ maskp, const float* __restrict__ feat,
    const float* __restrict__ Wq, const float* __restrict__ bq,
    const float* __restrict__ Wp1, const float* __restrict__ bp1,
    const float* __restrict__ bp2, const float* __restrict__ bo,
    const float* __restrict__ gamma, const float* __restrict__ beta,
    const u16t* __restrict__ idxp, const u16t* __restrict__ frags,
    const u16t* __restrict__ kbuf, const u16t* __restrict__ vbuf,
    float* __restrict__ outp) {
  const u16t* wp2f = frags + 2 * FR;
  const u16t* wof  = frags + 3 * FR;

  alignas(16) __shared__ u16t  hemb[32 * HSTR];     // hidT / embS / out-proj A
  alignas(16) __shared__ float featall[8 * DMODEL];
  alignas(16) __shared__ float oall[8 * DMODEL];    // attn out, then po
  alignas(16) __shared__ float lgs[2 * 8 * 16];
  __shared__ float red[4], red2[4];

  int c    = threadIdx.x;
  int lane = c & 63;
  int wv   = c >> 6;
  int quad = lane >> 4;
  int l15  = lane & 15;
  int hh   = c >> 5;
  int wv4  = wv * 4;

  float w1[6];
  #pragma unroll
  for (int p = 0; p < 6; ++p) w1[p] = Wp1[p * DMODEL + c];
  float b1v = bp1[c];
  float b2v = bp2[c];
  float bqv = bq[c];
  float bov = bo[c];
  float gam = gamma[c];
  float bet = beta[c];

  int qbase = blockIdx.x * 8;

  #pragma unroll
  for (int qi = 0; qi < 8; ++qi)
    featall[qi * DMODEL + c] = feat[(size_t)(qbase + qi) * DMODEL + c];
  __syncthreads();

  // q projection for all 8 queries (Wq read once per block)
  float qreg[8];
  #pragma unroll
  for (int qi = 0; qi < 8; ++qi) qreg[qi] = bqv;
  for (int d = 0; d < DMODEL; d += 4) {
    float wa = Wq[(size_t)(d + 0) * DMODEL + c];
    float wb = Wq[(size_t)(d + 1) * DMODEL + c];
    float wc = Wq[(size_t)(d + 2) * DMODEL + c];
    float wd = Wq[(size_t)(d + 3) * DMODEL + c];
    #pragma unroll
    for (int qi = 0; qi < 8; ++qi) {
      qreg[qi] += featall[qi * DMODEL + d + 0] * wa;
      qreg[qi] += featall[qi * DMODEL + d + 1] * wb;
      qreg[qi] += featall[qi * DMODEL + d + 2] * wc;
      qreg[qi] += featall[qi * DMODEL + d + 3] * wd;
    }
  }

  const float lsc = 0.17677669529663687f;

  for (int qp = 0; qp < 4; ++qp) {
    int g0 = qbase + qp * 2;
    int bb0 = (g0 >> 13) * NPTS;       // pair never crosses the batch boundary

    int ids[2][16];
    u16t kpre[2][16], vpre[2][16];
    float hreg[2][16];

    #pragma unroll
    for (int s = 0; s < 2; ++s) {
      int g = g0 + s;
      #pragma unroll
      for (int j = 0; j < 16; ++j) ids[s][j] = (int)idxp[(size_t)g * 16 + j];
      // prefetch k/v rows NOW; consumed after gelu+MFMA (~2k cycles later)
      #pragma unroll
      for (int j = 0; j < 16; ++j)
        kpre[s][j] = kbuf[(size_t)(bb0 + ids[s][j]) * DMODEL + c];
      #pragma unroll
      for (int j = 0; j < 16; ++j)
        vpre[s][j] = vbuf[(size_t)(bb0 + ids[s][j]) * DMODEL + c];
    }

    #pragma unroll
    for (int s = 0; s < 2; ++s) {
      int g = g0 + s;
      float qx = coords[(size_t)g * 3 + 0];
      float qy = coords[(size_t)g * 3 + 1];
      float qz = coords[(size_t)g * 3 + 2];
      float n0 = normals[(size_t)g * 3 + 0];
      float n1 = normals[(size_t)g * 3 + 1];
      float n2 = normals[(size_t)g * 3 + 2];
      #pragma unroll
      for (int j = 0; j < 16; ++j) {
        size_t cb = (size_t)(bb0 + ids[s][j]) * 3;
        float rx = qx - coords[cb + 0];
        float ry = qy - coords[cb + 1];
        float rz = qz - coords[cb + 2];
        float pre = b1v + rx * w1[0] + ry * w1[1] + rz * w1[2]
                        + n0 * w1[3] + n1 * w1[4] + n2 * w1[5];
        hreg[s][j] = gelu_exact(pre);
      }
    }

    __syncthreads();   // sync0: previous pair's hemb/lgs readers done
    #pragma unroll
    for (int s = 0; s < 2; ++s)
      #pragma unroll
      for (int j = 0; j < 16; ++j)
        hemb[(s * 16 + j) * HSTR + c] = f2b(hreg[s][j]);
    __syncthreads();   // sync1: hidT ready

    // emb GEMM: A (32x256 in LDS) @ Wp2 frags (L2); each bf feeds 2 MFMAs
    floatx4 acc[2][4];
    #pragma unroll
    for (int s = 0; s < 2; ++s)
      #pragma unroll
      for (int cc = 0; cc < 4; ++cc) acc[s][cc] = (floatx4){0.f, 0.f, 0.f, 0.f};
    #pragma unroll
    for (int ic = 0; ic < 8; ++ic) {
      short8 a0 = *(const short8*)(hemb + (l15)      * HSTR + ic * 32 + quad * 8);
      short8 a1 = *(const short8*)(hemb + (16 + l15) * HSTR + ic * 32 + quad * 8);
      #pragma unroll
      for (int cc = 0; cc < 4; ++cc) {
        short8 bf = *(const short8*)(wp2f + (((size_t)(ic * 16 + wv4 + cc) * 64 + lane) << 3));
        acc[0][cc] = __builtin_amdgcn_mfma_f32_16x16x32_bf16(a0, bf, acc[0][cc], 0, 0, 0);
        acc[1][cc] = __builtin_amdgcn_mfma_f32_16x16x32_bf16(a1, bf, acc[1][cc], 0, 0, 0);
      }
    }
    __syncthreads();   // sync2: all hidT reads done
    #pragma unroll
    for (int s = 0; s < 2; ++s)
      #pragma unroll
      for (int cc = 0; cc < 4; ++cc) {
        int cg = (wv4 + cc) * 16 + l15;
        #pragma unroll
        for (int r = 0; r < 4; ++r)
          hemb[(s * 16 + quad * 4 + r) * HSTR + cg] = f2b(acc[s][cc][r]);
      }
    __syncthreads();   // sync3: embS ready

    // logits for both queries (k from prefetch registers)
    float emb[2][16];
    #pragma unroll
    for (int s = 0; s < 2; ++s) {
      float qv = qreg[qp * 2 + s];
      #pragma unroll
      for (int j = 0; j < 16; ++j) {
        emb[s][j] = b2f(hemb[(s * 16 + j) * HSTR + c]) + b2v;
        float kc = b2f(kpre[s][j]) + emb[s][j];
        float p = qv * kc;
        p += __shfl_xor(p, 16, 32);
        p += __shfl_xor(p, 8, 32);
        p += __shfl_xor(p, 4, 32);
        p += __shfl_xor(p, 2, 32);
        p += __shfl_xor(p, 1, 32);
        if ((c & 31) == 0) {
          float mv = maskp[bb0 + ids[s][j]];
          lgs[(s * 8 + hh) * 16 + j] = (mv > 0.0f) ? (p * lsc) : -1e30f;
        }
      }
    }
    __syncthreads();   // sync4: lgs ready

    #pragma unroll
    for (int s = 0; s < 2; ++s) {
      float lg[16];
      #pragma unroll
      for (int j = 0; j < 16; ++j) lg[j] = lgs[(s * 8 + hh) * 16 + j];
      float m = lg[0];
      #pragma unroll
      for (int j = 1; j < 16; ++j) m = fmaxf(m, lg[j]);
      float wj[16];
      if (m > -1e29f) {
        float ssum = 0.0f;
        #pragma unroll
        for (int j = 0; j < 16; ++j) { wj[j] = expf(lg[j] - m); ssum += wj[j]; }
        float inv = 1.0f / ssum;
        #pragma unroll
        for (int j = 0; j < 16; ++j) wj[j] *= inv;
      } else {
        #pragma unroll
        for (int j = 0; j < 16; ++j) wj[j] = 0.0f;
      }
      float o = 0.0f;
      #pragma unroll
      for (int j = 0; j < 16; ++j)
        o += wj[j] * (b2f(vpre[s][j]) + emb[s][j]);
      oall[(qp * 2 + s) * DMODEL + c] = o;
    }
  }
  __syncthreads();   // oall complete

  // out projection via MFMA: A = oall (8 rows + 8 zero rows) bf16
  #pragma unroll
  for (int qi = 0; qi < 8; ++qi)
    hemb[qi * HSTR + c] = f2b(oall[qi * DMODEL + c]);
  #pragma unroll
  for (int qi = 8; qi < 16; ++qi)
    hemb[qi * HSTR + c] = 0;
  __syncthreads();

  floatx4 pacc[4];
  #pragma unroll
  for (int cc = 0; cc < 4; ++cc) pacc[cc] = (floatx4){0.f, 0.f, 0.f, 0.f};
  #pragma unroll
  for (int ic = 0; ic < 8; ++ic) {
    short8 af = *(const short8*)(hemb + l15 * HSTR + ic * 32 + quad * 8);
    #pragma unroll
    for (int cc = 0; cc < 4; ++cc) {
      short8 bf = *(const short8*)(wof + (((size_t)(ic * 16 + wv4 + cc) * 64 + lane) << 3));
      pacc[cc] = __builtin_amdgcn_mfma_f32_16x16x32_bf16(af, bf, pacc[cc], 0, 0, 0);
    }
  }
  __syncthreads();   // all oall reads done; overwrite with po
  #pragma unroll
  for (int cc = 0; cc < 4; ++cc) {
    int cg = (wv4 + cc) * 16 + l15;
    #pragma unroll
    for (int r = 0; r < 4; ++r) {
      int row = quad * 4 + r;
      if (row < 8) oall[row * DMODEL + cg] = pacc[cc][r];
    }
  }
  __syncthreads();

  // residual + LayerNorm + mask; f32 store
  for (int qi = 0; qi < 8; ++qi) {
    int g = qbase + qi;
    float mv = maskp[g];
    float h = featall[qi * DMODEL + c] + (oall[qi * DMODEL + c] + bov) * mv;
    float s = h, s2 = h * h;
    #pragma unroll
    for (int off = 32; off > 0; off >>= 1) {
      s  += __shfl_down(s,  off);
      s2 += __shfl_down(s2, off);
    }
    __syncthreads();
    if ((c & 63) == 0) { red[c >> 6] = s; red2[c >> 6] = s2; }
    __syncthreads();
    float mu  = (red[0]  + red[1]  + red[2]  + red[3])  * (1.0f / 256.0f);
    float ms  = (red2[0] + red2[1] + red2[2] + red2[3]) * (1.0f / 256.0f);
    float var = ms - mu * mu;
    float y = (h - mu) / sqrtf(var + 1e-6f) * gam + bet;
    y *= mv;
    outp[(size_t)g * DMODEL + c] = y;
  }
}

// ---------------------------------------------------------------------- host
extern "C" void kernel_launch(void* const* d_in, const int* in_sizes, int n_in,
                              void* d_out, int out_size, void* d_ws, size_t ws_size,
                              hipStream_t stream) {
  static const int EXP[18] = {4194304, 49152, 49152, 16384,
                              65536, 256, 65536, 256, 65536, 256, 65536, 256,
                              1536, 256, 65536, 256, 256, 256};
  bool sizes_ok = (n_in >= 18);
  if (sizes_ok) for (int i = 0; i < 18; ++i) sizes_ok = sizes_ok && (in_sizes[i] == EXP[i]);
  int fb = (out_size + 255) / 256;
  if (!sizes_ok) {
    fill_valf<<<fb, 256, 0, stream>>>((float*)d_out, out_size, 0.0f);
    return;
  }
  const size_t WS_NEED = 17825792;
  if (ws_size < WS_NEED) {
    fill_valf<<<fb, 256, 0, stream>>>((float*)d_out, out_size, 1.0f);
    return;
  }

  const float* feat    = (const float*)d_in[0];
  const float* coords  = (const float*)d_in[1];
  const float* normals = (const float*)d_in[2];
  const float* maskp   = (const float*)d_in[3];
  const float* Wq  = (const float*)d_in[4];
  const float* bq  = (const float*)d_in[5];
  const float* Wk  = (const float*)d_in[6];
  const float* bk  = (const float*)d_in[7];
  const float* Wv  = (const float*)d_in[8];
  const float* bv  = (const float*)d_in[9];
  const float* Wo  = (const float*)d_in[10];
  const float* bo  = (const float*)d_in[11];
  const float* Wp1 = (const float*)d_in[12];
  const float* bp1 = (const float*)d_in[13];
  const float* Wp2 = (const float*)d_in[14];
  const float* bp2 = (const float*)d_in[15];
  const float* gamma = (const float*)d_in[16];
  const float* beta  = (const float*)d_in[17];

  // Workspace (= 17,825,792 B exactly, proven):
  //   idx16 : u16  [16384*16]   @ 0          (524,288)
  //   frags : bf16 [4*65536]    @ 524,288    (524,288)  (Wk,Wv,Wp2,Wo)
  //   kb    : bf16 [16384*256]  @ 1,048,576  (8,388,608)
  //   vb    : bf16 [16384*256]  @ 9,437,184  (8,388,608)
  //   pd/pi (transposed [128][16384], 16 MB) alias kb+vb: dead before gemm_kv.
  char* ws = (char*)d_ws;
  u16t*  idx16 = (u16t*)(ws);
  u16t*  frags = (u16t*)(ws + 524288);
  u16t*  kb    = (u16t*)(ws + 1048576);
  u16t*  vb    = (u16t*)(ws + 9437184);
  float* pd    = (float*)(ws + 1048576);
  int*   pi    = (int*)(ws + 9437184);

  wprep<<<1024, 256, 0, stream>>>(Wk, Wv, Wp2, Wo, frags);
  knn_partial<<<512, 256, 0, stream>>>(coords, pd, pi);
  knn_merge<<<64, 256, 0, stream>>>(pd, pi, idx16);
  gemm_kv_mfma<<<dim3(256, 2), 256, 0, stream>>>(feat, frags, bk, bv, kb, vb);
  attn_mega<<<2048, 256, 0, stream>>>(coords, normals, maskp, feat,
                                      Wq, bq, Wp1, bp1, bp2, bo,
                                      gamma, beta, idx16, frags, kb, vb,
                                      (float*)d_out);
}